// Round 2
// baseline (200.706 us; speedup 1.0000x reference)
//
#include <hip/hip_runtime.h>

// GaussianPooling: fm[512,256,256] f32, keypoints[4096,2] int, out[4096,512] f32.
// 5x5 gaussian sigma=2, separable: k = g(dy)*g(dx)/s^2.
//
// R11 (= R10 + strip-size + prefetch changes):
//  - NSTRIP=8 (32-row strips, 36 staged rows): halo overhead 25% -> 12.5%,
//    staged bytes 167.8 -> 151 MB. Viable now because LDS-DMA staging is
//    fire-and-forget (R6's reg-round-trip staging choked at 4 blocks/CU;
//    that constraint is gone). 37.4 KB LDS -> 4 blocks/CU, 16 waves/CU.
//  - List-entry prefetch: issue list[t] BEFORE __syncthreads() (the barrier
//    drains vmcnt anyway, so the first entry is free); loop prefetches next.
//  - Kept from R10: LDS-DMA width=16 staging (wave stages a full 1 KB row:
//    per-lane global contiguous, LDS dest wave-uniform + lane*16), single
//    1024-thr bucket block (LDS rank = final position, no memset pass).
//  - Kept from R9: XCD write-merge swizzle -- out-line (n, c0..c0+15) is
//    written by 16 blocks (c0..c0+15, q(n)); they share b&7 -> same XCD ->
//    dword stores merge into full 64B lines in that XCD's L2.

#define NC  512
#define NH  256
#define NW  256
#define NKP 4096

#define NSTRIP 8               // y-strips of 32 rows
#define STRIP_SHIFT 5
#define SLICE_ROWS 36          // 32 + 2x2 halo
#define STR 260                // LDS row stride: +4 keeps 16B align, rotates banks

// ws layout (int32 offsets):
//   [0..8)                     cnt[8]   (written by bucket_kernel, no memset)
//   [8192 .. 8192+8*NKP)       packed lists (i | x<<12 | y<<20), stride NKP
#define WS_LIST_OFF_I 8192

// ---------------- bucket: ONE block, 1024 thr, 4 kp/thr ----------------
// Single block => LDS-atomic rank is the final within-strip position; counts
// are written directly (no zero pass, no cross-block reservation).
__global__ __launch_bounds__(1024) void bucket_kernel(
    const int* __restrict__ kp, unsigned* __restrict__ ws_i, int n_kp)
{
    __shared__ int hist[NSTRIP];
    const int t = threadIdx.x;

    if (t < NSTRIP) hist[t] = 0;
    __syncthreads();

    int      q[4], lr[4];
    unsigned pk[4];
    bool     valid[4];
#pragma unroll
    for (int j = 0; j < 4; ++j) {
        const int i = t + j * 1024;
        valid[j] = (i < n_kp);
        q[j] = 0; lr[j] = 0; pk[j] = 0u;
        if (valid[j]) {
            int x = kp[2 * i + 0];
            int y = kp[2 * i + 1];
            x = min(max(x, 2), NW - 3);
            y = min(max(y, 2), NH - 3);
            q[j]  = y >> STRIP_SHIFT;
            lr[j] = atomicAdd(&hist[q[j]], 1);
            pk[j] = (unsigned)i | ((unsigned)x << 12) | ((unsigned)y << 20);
        }
    }
    __syncthreads();

    if (t < NSTRIP) ws_i[t] = (unsigned)hist[t];   // final counts

#pragma unroll
    for (int j = 0; j < 4; ++j)
        if (valid[j])
            ws_i[WS_LIST_OFF_I + q[j] * NKP + lr[j]] = pk[j];
}

// ---------------- pool: 1-D grid of 4096, decode (c,q) with XCD swizzle ----------------
// b = (chunk&7) + 8*((chunk>>3)*128 + q*16 + lane16); the 16 blocks writing one
// out-line (same chunk, same q) share b&7 -> same XCD.
__global__ __launch_bounds__(256) void pool_kernel(
    const float* __restrict__ fm, const unsigned* __restrict__ ws_i,
    float* __restrict__ out)
{
    __shared__ float plane[SLICE_ROWS * STR];   // 37,440 B -> 4 blocks/CU

    const int b     = blockIdx.x;
    const int x7    = b & 7;
    const int inner = b >> 3;
    const int hi    = inner >> 7;          // chunk>>3, 0..3
    const int rem   = inner & 127;
    const int q     = rem >> 4;            // 0..7
    const int l16   = rem & 15;
    const int chunk = (hi << 3) | x7;      // 0..31
    const int c     = (chunk << 4) | l16;  // 0..511

    const int t    = threadIdx.x;
    const int w    = t >> 6;               // wave 0..3
    const int lane = t & 63;
    const int ybase = (q << STRIP_SHIFT) - 2;

    // overlap the scalar cnt load with staging latency
    const int cnt = (int)ws_i[q];

    // stage rows [ybase, ybase+35] clamped to [0,255] via LDS-DMA.
    // wave w, iter it -> row = w + 4*it (wave-uniform guard), 64 lanes x 16 B
    // = one full 1024 B row; LDS dest row*1040 + lane*16 (16B-aligned).
    const float* src = fm + ((size_t)c << 16);
#pragma unroll
    for (int it = 0; it < 9; ++it) {
        const int row = w + (it << 2);
        const int gr  = ybase + row;
        if ((unsigned)gr < 256u) {
            const float* g = src + ((size_t)gr << 8) + (lane << 2);
            float*       l = &plane[row * STR + (lane << 2)];
            __builtin_amdgcn_global_load_lds(
                (const __attribute__((address_space(1))) void*)g,
                (__attribute__((address_space(3))) void*)l,
                16, 0, 0);
        }
    }

    // gaussian weights (VALU work while loads fly, before the barrier)
    const float e1 = 0.8824969025845955f;  // exp(-1/8)
    const float e2 = 0.6065306597126334f;  // exp(-4/8)
    const float s  = 2.0f * (e1 + e2) + 1.0f;
    const float inv_s2 = 1.0f / (s * s);
    const float g[5] = {e2, e1, 1.0f, e1, e2};
    float gy[5];
#pragma unroll
    for (int i = 0; i < 5; i++) gy[i] = g[i] * inv_s2;

    const unsigned* list = ws_i + WS_LIST_OFF_I + q * NKP;

    // prefetch first entry; its latency drains with the staging vmcnt at the
    // barrier, so it's free.
    unsigned pk = (t < cnt) ? list[t] : 0u;

    __syncthreads();   // drains vmcnt -> LDS-DMA (and prefetch) complete

    for (int e = t; e < cnt; e += 256) {
        const int n  = (int)(pk & 0xFFFu);
        const int xc = (int)((pk >> 12) & 0xFFu);
        const int yc = (int)((pk >> 20) & 0xFFu);

        // software-prefetch next entry before the LDS-read/FMA body
        if (e + 256 < cnt) pk = list[e + 256];

        const int x0 = xc - 2;
        const int r  = x0 & 3;
        const int xa = x0 - r;
        float wx[8];
#pragma unroll
        for (int i = 0; i < 8; i++)
            wx[i] = (i >= r && i < r + 5) ? g[i - r] : 0.0f;

        const int lr0 = yc - (q << STRIP_SHIFT);   // plane row of (yc-2): 0..31
        float acc = 0.0f;
#pragma unroll
        for (int dy = 0; dy < 5; dy++) {
            const float* rowp = &plane[(lr0 + dy) * STR + xa];
            float4 a  = *(const float4*)rowp;
            float4 b4 = *(const float4*)(rowp + 4);
            acc += gy[dy] * (a.x * wx[0] + a.y * wx[1] + a.z * wx[2] + a.w * wx[3]
                           + b4.x * wx[4] + b4.y * wx[5] + b4.z * wx[6] + b4.w * wx[7]);
        }
        out[(size_t)n * NC + c] = acc;     // dword store; merges in same-XCD L2
    }
}

// ---------------- fallback (round-1 direct kernel) ----------------
__global__ __launch_bounds__(256) void gpool_direct_kernel(
    const float* __restrict__ fm, const int* __restrict__ kp,
    float* __restrict__ out)
{
    const int n = blockIdx.x;
    const int t = threadIdx.x;

    int x = kp[2 * n + 0];
    int y = kp[2 * n + 1];
    x = min(max(x, 2), NW - 3);
    y = min(max(y, 2), NH - 3);

    const float e1 = 0.8824969025845955f;
    const float e2 = 0.6065306597126334f;
    const float s  = 2.0f * (e1 + e2) + 1.0f;
    const float inv_s2 = 1.0f / (s * s);
    float g[5] = {e2, e1, 1.0f, e1, e2};
    float gy[5];
#pragma unroll
    for (int i = 0; i < 5; i++) gy[i] = g[i] * inv_s2;

    const int x0 = x - 2;
    const int r  = x0 & 3;
    const int xa = x0 - r;
    float wx[8];
#pragma unroll
    for (int i = 0; i < 8; i++)
        wx[i] = (i >= r && i < r + 5) ? g[i - r] : 0.0f;

    const float* base0 = fm + ((size_t)t * NH + (y - 2)) * NW + xa;
    const float* base1 = fm + ((size_t)(t + 256) * NH + (y - 2)) * NW + xa;

    float acc0 = 0.0f, acc1 = 0.0f;
#pragma unroll
    for (int dy = 0; dy < 5; dy++) {
        const float4* p0 = (const float4*)(base0 + dy * NW);
        const float4* p1 = (const float4*)(base1 + dy * NW);
        float4 a0 = p0[0], b0 = p0[1], a1 = p1[0], b1 = p1[1];
        acc0 += gy[dy] * (a0.x * wx[0] + a0.y * wx[1] + a0.z * wx[2] + a0.w * wx[3]
                        + b0.x * wx[4] + b0.y * wx[5] + b0.z * wx[6] + b0.w * wx[7]);
        acc1 += gy[dy] * (a1.x * wx[0] + a1.y * wx[1] + a1.z * wx[2] + a1.w * wx[3]
                        + b1.x * wx[4] + b1.y * wx[5] + b1.z * wx[6] + b1.w * wx[7]);
    }

    out[(size_t)n * NC + t]       = acc0;
    out[(size_t)n * NC + t + 256] = acc1;
}

extern "C" void kernel_launch(void* const* d_in, const int* in_sizes, int n_in,
                              void* d_out, int out_size, void* d_ws, size_t ws_size,
                              hipStream_t stream)
{
    const float* fm  = (const float*)d_in[0];
    const int*   kp  = (const int*)d_in[1];
    float*       out = (float*)d_out;
    const int n_kp   = in_sizes[1] / 2;   // 4096

    const size_t need = (WS_LIST_OFF_I + (size_t)NSTRIP * NKP) * sizeof(unsigned);
    if (ws_size >= need && n_kp == NKP) {
        unsigned* ws_i = (unsigned*)d_ws;

        bucket_kernel<<<1, 1024, 0, stream>>>(kp, ws_i, n_kp);

        pool_kernel<<<NC * NSTRIP, 256, 0, stream>>>(fm, ws_i, out);
    } else {
        gpool_direct_kernel<<<n_kp, 256, 0, stream>>>(fm, kp, out);
    }
}

// Round 3
// 199.016 us; speedup vs baseline: 1.0085x; 1.0085x over previous
//
#include <hip/hip_runtime.h>

// GaussianPooling: fm[512,256,256] f32, keypoints[4096,2] int, out[4096,512] f32.
// 5x5 gaussian sigma=2, separable: k = g(dy)*g(dx)/s^2.
//
// R12 (= R11 pool + fused in-block bucketing, ws-free, ONE kernel):
//  - Bucket kernel eliminated. Each block scans the raw kp array (32 KB,
//    L2-resident) and ballot-compacts its strip's entries into an LDS list.
//    Per-wave compaction (wave w owns kps [w*1024,(w+1)*1024)): ballot +
//    popcount prefix -> wave-local rank, NO atomics, no zeroing pass.
//  - vmcnt-order trick: the 8 int4 kp loads are issued BEFORE the 9 LDS-DMA
//    issues. vmcnt drains in order, so consuming kp regs waits vmcnt(9) --
//    kp loads done, staging DMAs still in flight. The scan runs entirely
//    under the staging HBM latency; the single __syncthreads then drains
//    everything (plane + list ready).
//  - Overflow robustness: per-wave list capacity CAPW=192 (mean 136, +5
//    sigma for this input). If cnt[w] > CAPW (adversarial input), the wave
//    deterministically rescans its range and processes rank >= CAPW entries
//    directly from the (fully staged) plane. Correct for any distribution.
//  - Kept from R11: NSTRIP=8 (36 staged rows, 12.5% halo), LDS-DMA width=16
//    row staging (per-lane global contiguous, wave-uniform LDS dest),
//    XCD write-merge swizzle (16 blocks writing one out-line share b&7 ->
//    same XCD -> dword stores merge into 64B lines in its L2).
//  - LDS: 36*260*4 + 4*192*4 + 16 = 40,528 B -> 4 blocks/CU, 16 waves/CU.

#define NC  512
#define NH  256
#define NW  256
#define NKP 4096

#define NSTRIP 8               // y-strips of 32 rows
#define STRIP_SHIFT 5
#define SLICE_ROWS 36          // 32 + 2x2 halo
#define STR 260                // LDS row stride: +4 keeps 16B align, rotates banks
#define CAPW 192               // per-wave list capacity (mean 136, sigma ~11)

// ---------------- fused pool: 1-D grid of 4096, decode (c,q) with XCD swizzle ----------------
// b = (chunk&7) + 8*((chunk>>3)*128 + q*16 + lane16); the 16 blocks writing one
// out-line (same chunk, same q) share b&7 -> same XCD.
__global__ __launch_bounds__(256) void pool_kernel(
    const float* __restrict__ fm, const int* __restrict__ kp,
    float* __restrict__ out)
{
    __shared__ float    plane[SLICE_ROWS * STR];   // 37,440 B
    __shared__ unsigned lds_list[4 * CAPW];        //  3,072 B
    __shared__ int      cnt[4];                    //     16 B

    const int b     = blockIdx.x;
    const int x7    = b & 7;
    const int inner = b >> 3;
    const int hi    = inner >> 7;          // chunk>>3, 0..3
    const int rem   = inner & 127;
    const int q     = rem >> 4;            // 0..7
    const int l16   = rem & 15;
    const int chunk = (hi << 3) | x7;      // 0..31
    const int c     = (chunk << 4) | l16;  // 0..511

    const int t    = threadIdx.x;
    const int w    = t >> 6;               // wave 0..3
    const int lane = t & 63;
    const int ybase = (q << STRIP_SHIFT) - 2;
    const unsigned long long lmlt = (1ull << lane) - 1ull;

    // ---- phase 1: issue the wave's 8 int4 kp loads (1024 kps/wave) FIRST ----
    const int4* kp4 = (const int4*)kp;     // 2 keypoints per int4
    int4 vv[8];
#pragma unroll
    for (int it = 0; it < 8; ++it)
        vv[it] = kp4[(w << 9) + (it << 6) + lane];

    // ---- phase 2: issue 9 LDS-DMA row stages (fire-and-forget) ----
    // wave w, iter it -> row = w + 4*it (wave-uniform guard); 64 lanes x 16 B
    // = one full 1024 B row; LDS dest row*1040 + lane*16 (16B-aligned).
    const float* src = fm + ((size_t)c << 16);
#pragma unroll
    for (int it = 0; it < 9; ++it) {
        const int row = w + (it << 2);
        const int gr  = ybase + row;
        if ((unsigned)gr < 256u) {
            const float* gp = src + ((size_t)gr << 8) + (lane << 2);
            float*       lp = &plane[row * STR + (lane << 2)];
            __builtin_amdgcn_global_load_lds(
                (const __attribute__((address_space(1))) void*)gp,
                (__attribute__((address_space(3))) void*)lp,
                16, 0, 0);
        }
    }

    // ---- phase 3: ballot-compact scan (consumes kp regs -> waits vmcnt(9),
    //      i.e. only the kp loads; staging DMAs keep flying underneath) ----
    int off = 0;
#pragma unroll
    for (int it = 0; it < 8; ++it) {
        const int i0 = (((w << 9) + (it << 6) + lane) << 1);
        // keypoint 2*idx4
        {
            const int x = min(max(vv[it].x, 2), NW - 3);
            const int y = min(max(vv[it].y, 2), NH - 3);
            const bool m = ((y >> STRIP_SHIFT) == q);
            const unsigned long long bal = __ballot(m);
            const int pos = off + __popcll(bal & lmlt);
            if (m && pos < CAPW)
                lds_list[w * CAPW + pos] =
                    (unsigned)i0 | ((unsigned)x << 12) | ((unsigned)y << 20);
            off += __popcll(bal);
        }
        // keypoint 2*idx4+1
        {
            const int x = min(max(vv[it].z, 2), NW - 3);
            const int y = min(max(vv[it].w, 2), NH - 3);
            const bool m = ((y >> STRIP_SHIFT) == q);
            const unsigned long long bal = __ballot(m);
            const int pos = off + __popcll(bal & lmlt);
            if (m && pos < CAPW)
                lds_list[w * CAPW + pos] =
                    (unsigned)(i0 + 1) | ((unsigned)x << 12) | ((unsigned)y << 20);
            off += __popcll(bal);
        }
    }
    if (lane == 0) cnt[w] = off;           // full count (may exceed CAPW)

    // gaussian weights (VALU while staging drains)
    const float e1 = 0.8824969025845955f;  // exp(-1/8)
    const float e2 = 0.6065306597126334f;  // exp(-4/8)
    const float s  = 2.0f * (e1 + e2) + 1.0f;
    const float inv_s2 = 1.0f / (s * s);
    const float g[5] = {e2, e1, 1.0f, e1, e2};
    float gy[5];
#pragma unroll
    for (int i = 0; i < 5; i++) gy[i] = g[i] * inv_s2;

    __syncthreads();   // drains vmcnt+lgkm -> plane AND lists ready

    // ---- phase 4: process the 4 per-wave segments ----
    for (int seg = 0; seg < 4; ++seg) {
        const int cs = min(cnt[seg], CAPW);
        for (int e = t; e < cs; e += 256) {
            const unsigned pk = lds_list[seg * CAPW + e];
            const int n  = (int)(pk & 0xFFFu);
            const int xc = (int)((pk >> 12) & 0xFFu);
            const int yc = (int)((pk >> 20) & 0xFFu);

            const int x0 = xc - 2;
            const int r  = x0 & 3;
            const int xa = x0 - r;
            float wx[8];
#pragma unroll
            for (int i = 0; i < 8; i++)
                wx[i] = (i >= r && i < r + 5) ? g[i - r] : 0.0f;

            const int lr0 = yc - (q << STRIP_SHIFT);   // plane row of (yc-2)
            float acc = 0.0f;
#pragma unroll
            for (int dy = 0; dy < 5; dy++) {
                const float* rowp = &plane[(lr0 + dy) * STR + xa];
                float4 a  = *(const float4*)rowp;
                float4 b4 = *(const float4*)(rowp + 4);
                acc += gy[dy] * (a.x * wx[0] + a.y * wx[1] + a.z * wx[2] + a.w * wx[3]
                               + b4.x * wx[4] + b4.y * wx[5] + b4.z * wx[6] + b4.w * wx[7]);
            }
            out[(size_t)n * NC + c] = acc;   // dword store; merges in same-XCD L2
        }
    }

    // ---- phase 5: overflow fallback (deterministic rescan; wave-uniform,
    //      never taken for this input distribution) ----
    if (cnt[w] > CAPW) {
        int off2 = 0;
#pragma unroll 1
        for (int it = 0; it < 8; ++it) {
            const int4 v = kp4[(w << 9) + (it << 6) + lane];
            const int i0 = (((w << 9) + (it << 6) + lane) << 1);
#pragma unroll
            for (int half = 0; half < 2; ++half) {
                const int xr = half ? v.z : v.x;
                const int yr = half ? v.w : v.y;
                const int x = min(max(xr, 2), NW - 3);
                const int y = min(max(yr, 2), NH - 3);
                const bool m = ((y >> STRIP_SHIFT) == q);
                const unsigned long long bal = __ballot(m);
                const int pos = off2 + __popcll(bal & lmlt);
                if (m && pos >= CAPW) {
                    const int x0 = x - 2;
                    const int r  = x0 & 3;
                    const int xa = x0 - r;
                    float wx[8];
#pragma unroll
                    for (int i = 0; i < 8; i++)
                        wx[i] = (i >= r && i < r + 5) ? g[i - r] : 0.0f;
                    const int lr0 = y - (q << STRIP_SHIFT);
                    float acc = 0.0f;
#pragma unroll
                    for (int dy = 0; dy < 5; dy++) {
                        const float* rowp = &plane[(lr0 + dy) * STR + xa];
                        float4 a  = *(const float4*)rowp;
                        float4 b4 = *(const float4*)(rowp + 4);
                        acc += gy[dy] * (a.x * wx[0] + a.y * wx[1] + a.z * wx[2] + a.w * wx[3]
                                       + b4.x * wx[4] + b4.y * wx[5] + b4.z * wx[6] + b4.w * wx[7]);
                    }
                    out[(size_t)(i0 + half) * NC + c] = acc;
                }
                off2 += __popcll(bal);
            }
        }
    }
}

// ---------------- fallback (round-1 direct kernel) ----------------
__global__ __launch_bounds__(256) void gpool_direct_kernel(
    const float* __restrict__ fm, const int* __restrict__ kp,
    float* __restrict__ out)
{
    const int n = blockIdx.x;
    const int t = threadIdx.x;

    int x = kp[2 * n + 0];
    int y = kp[2 * n + 1];
    x = min(max(x, 2), NW - 3);
    y = min(max(y, 2), NH - 3);

    const float e1 = 0.8824969025845955f;
    const float e2 = 0.6065306597126334f;
    const float s  = 2.0f * (e1 + e2) + 1.0f;
    const float inv_s2 = 1.0f / (s * s);
    float g[5] = {e2, e1, 1.0f, e1, e2};
    float gy[5];
#pragma unroll
    for (int i = 0; i < 5; i++) gy[i] = g[i] * inv_s2;

    const int x0 = x - 2;
    const int r  = x0 & 3;
    const int xa = x0 - r;
    float wx[8];
#pragma unroll
    for (int i = 0; i < 8; i++)
        wx[i] = (i >= r && i < r + 5) ? g[i - r] : 0.0f;

    const float* base0 = fm + ((size_t)t * NH + (y - 2)) * NW + xa;
    const float* base1 = fm + ((size_t)(t + 256) * NH + (y - 2)) * NW + xa;

    float acc0 = 0.0f, acc1 = 0.0f;
#pragma unroll
    for (int dy = 0; dy < 5; dy++) {
        const float4* p0 = (const float4*)(base0 + dy * NW);
        const float4* p1 = (const float4*)(base1 + dy * NW);
        float4 a0 = p0[0], b0 = p0[1], a1 = p1[0], b1 = p1[1];
        acc0 += gy[dy] * (a0.x * wx[0] + a0.y * wx[1] + a0.z * wx[2] + a0.w * wx[3]
                        + b0.x * wx[4] + b0.y * wx[5] + b0.z * wx[6] + b0.w * wx[7]);
        acc1 += gy[dy] * (a1.x * wx[0] + a1.y * wx[1] + a1.z * wx[2] + a1.w * wx[3]
                        + b1.x * wx[4] + b1.y * wx[5] + b1.z * wx[6] + b1.w * wx[7]);
    }

    out[(size_t)n * NC + t]       = acc0;
    out[(size_t)n * NC + t + 256] = acc1;
}

extern "C" void kernel_launch(void* const* d_in, const int* in_sizes, int n_in,
                              void* d_out, int out_size, void* d_ws, size_t ws_size,
                              hipStream_t stream)
{
    const float* fm  = (const float*)d_in[0];
    const int*   kp  = (const int*)d_in[1];
    float*       out = (float*)d_out;
    const int n_kp   = in_sizes[1] / 2;   // 4096

    (void)d_ws; (void)ws_size;            // workspace-free

    if (n_kp == NKP) {
        pool_kernel<<<NC * NSTRIP, 256, 0, stream>>>(fm, kp, out);
    } else {
        gpool_direct_kernel<<<n_kp, 256, 0, stream>>>(fm, kp, out);
    }
}

// Round 4
// 194.183 us; speedup vs baseline: 1.0336x; 1.0249x over previous
//
#include <hip/hip_runtime.h>

// GaussianPooling: fm[512,256,256] f32, keypoints[4096,2] int, out[4096,512] f32.
// 5x5 gaussian sigma=2, separable: k = g(dy)*g(dx)/s^2.
//
// R13 (channel-group pipeline):
//  - Block = (strip q, group of 8 consecutive channels), grid 8*64 = 512
//    blocks = exactly 2/CU (78 KB LDS), single cohort.
//  - Double-buffered plane (2 x 36x260 f32 = 74.9 KB). Per channel i:
//    __syncthreads (drains stage(i) DMA) -> issue stage(i+1) into other buf
//    (fire-and-forget LDS-DMA) -> compute(i). Stage(i+1) flies under
//    compute(i): the guide's minimum 2-phase pipeline with plain syncs.
//  - kp scan + ballot-compaction ONCE per block (was once per channel-block:
//    8x less kp L2 traffic, 8x fewer scans).
//  - Per-entry decode (n, xa, lr0, wx[8]) hoisted out of the channel loop;
//    results accumulate in res[seg][ch] (all indices compile-time static).
//  - Output: per entry ONE 32 B contiguous write (two float4) covering the
//    block's 8 channels, instead of 8 scattered dwords. 4x fewer store
//    instrs; line-merge in L2 now needs only the paired group (g^1, same
//    b&7 -> same XCD) instead of 16 distinct blocks.
//  - Kept: NSTRIP=8 (36 staged rows), LDS-DMA width=16 row staging
//    (per-lane global contiguous, wave-uniform LDS dest), XCD swizzle.
//  - Overflow fallback (cnt>CAPW, never taken for this input): wave rescans
//    its kp range and computes rank>=CAPW entries straight from global fm.

#define NC  512
#define NH  256
#define NW  256
#define NKP 4096

#define NSTRIP 8               // y-strips of 32 rows
#define STRIP_SHIFT 5
#define SLICE_ROWS 36          // 32 + 2x2 halo
#define STR 260                // LDS row stride: +4 keeps 16B align, rotates banks
#define PLANE (SLICE_ROWS * STR)
#define CAPW 192               // per-wave list capacity (mean 128, sigma ~11)
#define G 8                    // channels per block

// ---------------- fused pool ----------------
// b = (p&7) + 8*((p>>3)*16 + q*2 + m), p = channel-pair 0..31, m = member.
// Groups g=2p and g=2p+1 (which share out-lines) share b&7 -> same XCD.
__global__ __launch_bounds__(256) void pool_kernel(
    const float* __restrict__ fm, const int* __restrict__ kp,
    float* __restrict__ out)
{
    __shared__ float    plane[2 * PLANE];          // 74,880 B
    __shared__ unsigned lds_list[4 * CAPW];        //  3,072 B
    __shared__ int      cnt[4];                    //     16 B

    const int b     = blockIdx.x;
    const int x7    = b & 7;
    const int inner = b >> 3;          // 0..63
    const int hi    = inner >> 4;      // p>>3, 0..3
    const int rem   = inner & 15;
    const int q     = rem >> 1;        // 0..7
    const int m     = rem & 1;
    const int p     = (hi << 3) | x7;  // 0..31
    const int gidx  = (p << 1) | m;    // 0..63
    const int c0    = gidx << 3;       // first channel of the group

    const int t    = threadIdx.x;
    const int w    = t >> 6;           // wave 0..3
    const int lane = t & 63;
    const int ybase = (q << STRIP_SHIFT) - 2;
    const unsigned long long lmlt = (1ull << lane) - 1ull;

    // ---- issue the wave's 8 int4 kp loads (1024 kps/wave) FIRST ----
    const int4* kp4 = (const int4*)kp;     // 2 keypoints per int4
    int4 vv[8];
#pragma unroll
    for (int it = 0; it < 8; ++it)
        vv[it] = kp4[(w << 9) + (it << 6) + lane];

    // ---- stage channel c0 into buffer 0 (fire-and-forget) ----
    // wave w stages rows w+4k, k=0..8; 64 lanes x 16 B = one full 1 KB row;
    // LDS dest row*1040 + lane*16 (wave-uniform base, 16B aligned).
#define STAGE(CH, BASE)                                                        \
    do {                                                                       \
        const float* _src = fm + ((size_t)(CH) << 16);                         \
        _Pragma("unroll")                                                      \
        for (int _k = 0; _k < 9; ++_k) {                                       \
            const int _row = w + (_k << 2);                                    \
            const int _gr  = ybase + _row;                                     \
            if ((unsigned)_gr < 256u) {                                        \
                const float* _gp = _src + (_gr << 8) + (lane << 2);            \
                float*       _lp = (BASE) + _row * STR + (lane << 2);          \
                __builtin_amdgcn_global_load_lds(                              \
                    (const __attribute__((address_space(1))) void*)_gp,        \
                    (__attribute__((address_space(3))) void*)_lp, 16, 0, 0);   \
            }                                                                  \
        }                                                                      \
    } while (0)

    STAGE(c0, plane);

    // ---- ballot-compact scan (consumes kp regs -> waits only the kp loads;
    //      staging DMAs keep flying underneath) ----
    int off = 0;
#pragma unroll
    for (int it = 0; it < 8; ++it) {
        const int i0 = (((w << 9) + (it << 6) + lane) << 1);
        {
            const int x = min(max(vv[it].x, 2), NW - 3);
            const int y = min(max(vv[it].y, 2), NH - 3);
            const bool mm = ((y >> STRIP_SHIFT) == q);
            const unsigned long long bal = __ballot(mm);
            const int pos = off + __popcll(bal & lmlt);
            if (mm && pos < CAPW)
                lds_list[w * CAPW + pos] =
                    (unsigned)i0 | ((unsigned)x << 12) | ((unsigned)y << 20);
            off += __popcll(bal);
        }
        {
            const int x = min(max(vv[it].z, 2), NW - 3);
            const int y = min(max(vv[it].w, 2), NH - 3);
            const bool mm = ((y >> STRIP_SHIFT) == q);
            const unsigned long long bal = __ballot(mm);
            const int pos = off + __popcll(bal & lmlt);
            if (mm && pos < CAPW)
                lds_list[w * CAPW + pos] =
                    (unsigned)(i0 + 1) | ((unsigned)x << 12) | ((unsigned)y << 20);
            off += __popcll(bal);
        }
    }
    if (lane == 0) cnt[w] = off;           // full count (may exceed CAPW)

    // gaussian weights
    const float e1 = 0.8824969025845955f;  // exp(-1/8)
    const float e2 = 0.6065306597126334f;  // exp(-4/8)
    const float s  = 2.0f * (e1 + e2) + 1.0f;
    const float inv_s2 = 1.0f / (s * s);
    const float g[5] = {e2, e1, 1.0f, e1, e2};
    float gy[5];
#pragma unroll
    for (int i = 0; i < 5; i++) gy[i] = g[i] * inv_s2;

    // per-entry state (decoded once, reused for all 8 channels)
    bool  ev[4];
    int   en[4], elr0[4];
    int   exa[4];
    float ewx[4][8];
    float res[4][G];

    // ---- channel pipeline: sync -> issue next stage -> compute current ----
#pragma unroll
    for (int i = 0; i < G; ++i) {
        __syncthreads();   // drains vmcnt: stage(i) complete; lists visible (i==0)

        if (i < G - 1)
            STAGE(c0 + i + 1, plane + ((i + 1) & 1) * PLANE);

        if (i == 0) {
            // decode this thread's (up to 4) entries, once
#pragma unroll
            for (int seg = 0; seg < 4; ++seg) {
                const int cs = min(cnt[seg], CAPW);
                ev[seg] = (t < cs);
                en[seg] = 0; exa[seg] = 0; elr0[seg] = 0;
#pragma unroll
                for (int j = 0; j < 8; ++j) ewx[seg][j] = 0.0f;
                if (ev[seg]) {
                    const unsigned pk = lds_list[seg * CAPW + t];
                    const int n  = (int)(pk & 0xFFFu);
                    const int xc = (int)((pk >> 12) & 0xFFu);
                    const int yc = (int)((pk >> 20) & 0xFFu);
                    const int x0 = xc - 2;
                    const int r  = x0 & 3;
                    en[seg]   = n;
                    exa[seg]  = x0 - r;
                    elr0[seg] = yc - (q << STRIP_SHIFT);
#pragma unroll
                    for (int j = 0; j < 8; ++j)
                        ewx[seg][j] = (j >= r && j < r + 5) ? g[j - r] : 0.0f;
                }
            }
        }

        const float* cur = plane + (i & 1) * PLANE;
#pragma unroll
        for (int seg = 0; seg < 4; ++seg) {
            if (ev[seg]) {
                float acc = 0.0f;
#pragma unroll
                for (int dy = 0; dy < 5; ++dy) {
                    const float* rowp = &cur[(elr0[seg] + dy) * STR + exa[seg]];
                    float4 a  = *(const float4*)rowp;
                    float4 b4 = *(const float4*)(rowp + 4);
                    acc += gy[dy] * (a.x * ewx[seg][0] + a.y * ewx[seg][1]
                                   + a.z * ewx[seg][2] + a.w * ewx[seg][3]
                                   + b4.x * ewx[seg][4] + b4.y * ewx[seg][5]
                                   + b4.z * ewx[seg][6] + b4.w * ewx[seg][7]);
                }
                res[seg][i] = acc;
            }
        }
    }

    // ---- store: one 32 B contiguous write per entry (two float4) ----
#pragma unroll
    for (int seg = 0; seg < 4; ++seg) {
        if (ev[seg]) {
            float4 s0 = make_float4(res[seg][0], res[seg][1], res[seg][2], res[seg][3]);
            float4 s1 = make_float4(res[seg][4], res[seg][5], res[seg][6], res[seg][7]);
            float* op = out + (size_t)en[seg] * NC + c0;
            *(float4*)op       = s0;
            *((float4*)op + 1) = s1;
        }
    }

    // ---- overflow fallback (cnt[w] > CAPW, wave-uniform; never taken for
    //      this input). Rank >= CAPW entries computed straight from global fm. ----
    if (cnt[w] > CAPW) {
        int off2 = 0;
#pragma unroll 1
        for (int it = 0; it < 8; ++it) {
            const int4 v = kp4[(w << 9) + (it << 6) + lane];
            const int i0 = (((w << 9) + (it << 6) + lane) << 1);
#pragma unroll
            for (int half = 0; half < 2; ++half) {
                const int xr = half ? v.z : v.x;
                const int yr = half ? v.w : v.y;
                const int x = min(max(xr, 2), NW - 3);
                const int y = min(max(yr, 2), NH - 3);
                const bool mm = ((y >> STRIP_SHIFT) == q);
                const unsigned long long bal = __ballot(mm);
                const int pos = off2 + __popcll(bal & lmlt);
                if (mm && pos >= CAPW) {
                    const int x0 = x - 2;
                    const int r  = x0 & 3;
                    const int xa = x0 - r;
                    float wx[8];
#pragma unroll
                    for (int j = 0; j < 8; ++j)
                        wx[j] = (j >= r && j < r + 5) ? g[j - r] : 0.0f;
#pragma unroll 1
                    for (int ch = 0; ch < G; ++ch) {
                        const float* base = fm + (((size_t)(c0 + ch)) << 16)
                                          + (size_t)(y - 2) * NW + xa;
                        float acc = 0.0f;
#pragma unroll
                        for (int dy = 0; dy < 5; ++dy) {
                            const float4* p0 = (const float4*)(base + dy * NW);
                            float4 a = p0[0], b4 = p0[1];
                            acc += gy[dy] * (a.x * wx[0] + a.y * wx[1] + a.z * wx[2]
                                           + a.w * wx[3] + b4.x * wx[4] + b4.y * wx[5]
                                           + b4.z * wx[6] + b4.w * wx[7]);
                        }
                        out[(size_t)(i0 + half) * NC + c0 + ch] = acc;
                    }
                }
                off2 += __popcll(bal);
            }
        }
    }
#undef STAGE
}

// ---------------- fallback (round-1 direct kernel) ----------------
__global__ __launch_bounds__(256) void gpool_direct_kernel(
    const float* __restrict__ fm, const int* __restrict__ kp,
    float* __restrict__ out)
{
    const int n = blockIdx.x;
    const int t = threadIdx.x;

    int x = kp[2 * n + 0];
    int y = kp[2 * n + 1];
    x = min(max(x, 2), NW - 3);
    y = min(max(y, 2), NH - 3);

    const float e1 = 0.8824969025845955f;
    const float e2 = 0.6065306597126334f;
    const float s  = 2.0f * (e1 + e2) + 1.0f;
    const float inv_s2 = 1.0f / (s * s);
    float g[5] = {e2, e1, 1.0f, e1, e2};
    float gy[5];
#pragma unroll
    for (int i = 0; i < 5; i++) gy[i] = g[i] * inv_s2;

    const int x0 = x - 2;
    const int r  = x0 & 3;
    const int xa = x0 - r;
    float wx[8];
#pragma unroll
    for (int i = 0; i < 8; i++)
        wx[i] = (i >= r && i < r + 5) ? g[i - r] : 0.0f;

    const float* base0 = fm + ((size_t)t * NH + (y - 2)) * NW + xa;
    const float* base1 = fm + ((size_t)(t + 256) * NH + (y - 2)) * NW + xa;

    float acc0 = 0.0f, acc1 = 0.0f;
#pragma unroll
    for (int dy = 0; dy < 5; dy++) {
        const float4* p0 = (const float4*)(base0 + dy * NW);
        const float4* p1 = (const float4*)(base1 + dy * NW);
        float4 a0 = p0[0], b0 = p0[1], a1 = p1[0], b1 = p1[1];
        acc0 += gy[dy] * (a0.x * wx[0] + a0.y * wx[1] + a0.z * wx[2] + a0.w * wx[3]
                        + b0.x * wx[4] + b0.y * wx[5] + b0.z * wx[6] + b0.w * wx[7]);
        acc1 += gy[dy] * (a1.x * wx[0] + a1.y * wx[1] + a1.z * wx[2] + a1.w * wx[3]
                        + b1.x * wx[4] + b1.y * wx[5] + b1.z * wx[6] + b1.w * wx[7]);
    }

    out[(size_t)n * NC + t]       = acc0;
    out[(size_t)n * NC + t + 256] = acc1;
}

extern "C" void kernel_launch(void* const* d_in, const int* in_sizes, int n_in,
                              void* d_out, int out_size, void* d_ws, size_t ws_size,
                              hipStream_t stream)
{
    const float* fm  = (const float*)d_in[0];
    const int*   kp  = (const int*)d_in[1];
    float*       out = (float*)d_out;
    const int n_kp   = in_sizes[1] / 2;   // 4096

    (void)d_ws; (void)ws_size;            // workspace-free

    if (n_kp == NKP) {
        pool_kernel<<<NSTRIP * (NC / G), 256, 0, stream>>>(fm, kp, out);
    } else {
        gpool_direct_kernel<<<n_kp, 256, 0, stream>>>(fm, kp, out);
    }
}